// Round 13
// baseline (842.024 us; speedup 1.0000x reference)
//
#include <hip/hip_runtime.h>

#define S_TOK 16384   // S*N tokens
#define D_DIM 1024
#define F_DIM 4096
#define E_NUM 8

#define BM 256
#define BN 256
#define BK 64
#define MT_MAX 72     // sum_e ceil(cnt_e/256) <= 64 + 8 = 72

typedef short bf16x8 __attribute__((ext_vector_type(8)));
typedef float f32x4 __attribute__((ext_vector_type(4)));
typedef unsigned short ushort_t;

static __device__ __forceinline__ unsigned short f32_bf16(float f) {
  unsigned u = __float_as_uint(f);
  return (unsigned short)((u + 0x7FFFu + ((u >> 16) & 1u)) >> 16);
}

static __device__ __forceinline__ unsigned int pack_bf16x2(float a, float b) {
  unsigned ua = __float_as_uint(a);
  unsigned ub = __float_as_uint(b);
  unsigned lo = (ua + 0x7FFFu + ((ua >> 16) & 1u)) >> 16;
  unsigned hi = (ub + 0x7FFFu + ((ub >> 16) & 1u)) & 0xFFFF0000u;
  return lo | hi;
}

static __device__ __forceinline__ uint2 cvt_f4_bf4(const float4 v) {
  uint2 r;
  r.x = pack_bf16x2(v.x, v.y);
  r.y = pack_bf16x2(v.z, v.w);
  return r;
}

static __device__ __forceinline__ void load_lds16(const void* g, void* l) {
  __builtin_amdgcn_global_load_lds(g, l, 16, 0, 0);
}

// exact-enough gelu: Abramowitz-Stegun 7.1.26 erf (|err|<=1.5e-7) + fast exp.
static __device__ __forceinline__ float gelu_f(float v) {
  const float u = fabsf(v) * 0.70710678118654752f;
  const float t = 1.0f / (1.0f + 0.3275911f * u);
  const float poly = t * (0.254829592f + t * (-0.284496736f + t * (1.421413741f +
                     t * (-1.453152027f + t * 1.061405429f))));
  const float erfa = 1.0f - poly * __expf(-u * u);
  const float erfv = (v >= 0.0f) ? erfa : -erfa;
  return 0.5f * v * (1.0f + erfv);
}

// ---------------- zero counts ----------------
__global__ void zero_counts_kernel(int* counts) {
  if (threadIdx.x < E_NUM) counts[threadIdx.x] = 0;
}

// ---------------- fp32 -> bf16 cast of W1 and W2 in one launch ----------------
__global__ void cast2_kernel(const float* __restrict__ w1, ushort_t* __restrict__ o1,
                             const float* __restrict__ w2, ushort_t* __restrict__ o2) {
  const int half = 16384;
  const float* src = (blockIdx.x < half) ? w1 : w2;
  ushort_t* dst = (blockIdx.x < half) ? o1 : o2;
  const int b = (blockIdx.x < half) ? blockIdx.x : (blockIdx.x - half);
  const size_t base = ((size_t)b * blockDim.x + threadIdx.x) * 8;
  const float4 v0 = *(const float4*)(src + base);
  const float4 v1 = *(const float4*)(src + base + 4);
  const uint2 a = cvt_f4_bf4(v0), c = cvt_f4_bf4(v1);
  uint4 w; w.x = a.x; w.y = a.y; w.z = c.x; w.w = c.y;
  *(uint4*)(dst + base) = w;
}

// ---------------- gating (+ x cast to bf16) ----------------
__global__ void gate_kernel(const float* __restrict__ x,
                            const float* __restrict__ Wg,
                            ushort_t* __restrict__ xbf,
                            float* __restrict__ prob,
                            int* __restrict__ counts,
                            int* __restrict__ tok_list) {
  const int wv = threadIdx.x >> 6;
  const int lane = threadIdx.x & 63;
  const int t = blockIdx.x * 4 + wv;
  const float* xr = x + (size_t)t * D_DIM;
  ushort_t* xb = xbf + (size_t)t * D_DIM;

  float acc[E_NUM];
#pragma unroll
  for (int e = 0; e < E_NUM; ++e) acc[e] = 0.0f;

#pragma unroll
  for (int i = 0; i < 4; ++i) {
    const int k = i * 256 + lane * 4;
    const float4 v = *(const float4*)(xr + k);
    *(uint2*)(xb + k) = cvt_f4_bf4(v);
#pragma unroll
    for (int e = 0; e < E_NUM; ++e) {
      const float4 w = *(const float4*)(Wg + e * D_DIM + k);
      acc[e] += v.x * w.x + v.y * w.y + v.z * w.z + v.w * w.w;
    }
  }
#pragma unroll
  for (int e = 0; e < E_NUM; ++e) {
#pragma unroll
    for (int off = 32; off > 0; off >>= 1)
      acc[e] += __shfl_xor(acc[e], off, 64);
  }
  if (lane == 0) {
    float m = acc[0]; int bi = 0;
#pragma unroll
    for (int e = 1; e < E_NUM; ++e) {
      if (acc[e] > m) { m = acc[e]; bi = e; }
    }
    float s = 0.0f;
#pragma unroll
    for (int e = 0; e < E_NUM; ++e) s += expf(acc[e] - m);
    prob[t] = 1.0f / s;             // softmax prob of the argmax logit
    int p = atomicAdd(&counts[bi], 1);
    tok_list[bi * S_TOK + p] = t;
  }
}

// ---------------- tile plan: dense (expert, m0) table, BM=256 ----------------
__global__ void plan_kernel(const int* __restrict__ counts, int* __restrict__ plan) {
  if (threadIdx.x == 0) {
    int t = 0;
    for (int e = 0; e < E_NUM; ++e) {
      const int nt = (counts[e] + BM - 1) / BM;
      for (int i = 0; i < nt; ++i) {
        plan[1 + t] = e;
        plan[1 + MT_MAX + t] = i * BM;
        ++t;
      }
    }
    plan[0] = t;
  }
}

// ---------------- grouped GEMM: 256^2, BK=64, dbuf, ONE barrier/step ---------
// m230-V0 / m248v2-2ph recipe, plain HIP (no inline asm): per K-step, issue
// the 8 global_load_lds for tile t+1 into buf^1 FIRST, then 24 ds_read_b128 +
// 64 MFMA per wave on buf, then a single __syncthreads (vmcnt+lgkm drain +
// barrier). The prefetch flies under the whole compute phase; with dbuf one
// barrier per step proves both "next staged" and "cur fully read".
// 8 waves as 2M x 4N; per-wave output 128 x 64 (acc[8][4], 128 AGPR).
// LDS 128 KB -> 1 block/CU (occupancy intentionally low; in-step overlap
// carries the pipeline, per m230/m201).
// Swizzle (proven zero-conflict): 128B row = 8 x 16B slots, phys = log ^
// (row&7); applied to the global SOURCE (LDS dest linear, rule #21) and to
// ds_read addrs.
template <int KDIM, int NDIM, int EPI>
__launch_bounds__(512, 2)
__global__ void ffn_kernel(const ushort_t* __restrict__ A,
                           const ushort_t* __restrict__ B,
                           const float* __restrict__ bias,
                           const float* __restrict__ prob,
                           const int* __restrict__ counts,
                           const int* __restrict__ tok_list,
                           const int* __restrict__ plan,
                           ushort_t* __restrict__ Hout,
                           float* __restrict__ out) {
  constexpr int NT = NDIM / BN;
  constexpr int NK = KDIM / BK;
  const int ntiles = plan[0];
  const int live = ntiles * NT;
  if (blockIdx.x >= live) return;
  // runtime-bijective XCD swizzle over the LIVE range (m204 formula)
  const int q = live >> 3, r = live & 7;
  const int xcd = blockIdx.x & 7, idx = blockIdx.x >> 3;
  const int wg = (xcd < r ? xcd * (q + 1) : r * (q + 1) + (xcd - r) * q) + idx;
  const int tile = wg / NT;            // m slow, n fast: A-panel hot per XCD
  const int n0 = (wg % NT) * BN;
  const int e = plan[1 + tile];
  const int m0 = plan[1 + MT_MAX + tile];
  const int cnt = counts[e];

  __shared__ ushort_t As[2][BM * BK];   // 2 x 32 KB
  __shared__ ushort_t Bs[2][BN * BK];   // 2 x 32 KB  (128 KB total)

  const int tid = threadIdx.x;
  const int lane = tid & 63;
  const int w = tid >> 6;              // 0..7
  const int wr2 = (w >> 2) * 128;      // 0 / 128   : m-half
  const int wc4 = (w & 3) * 64;        // 0..192    : n-quarter
  const int l15 = lane & 15;
  const int l4  = lane >> 4;

  // staging: instr covers 64 rows (8 thr/row); wave w -> rows +w*8..w*8+8.
  // lane l -> row +(l>>3), 16B slot (l&7); source pre-swizzled:
  // logical slot = (l&7) ^ (row&7) = (l&7) ^ (l>>3)   (bases are mult of 8)
  const int sub = lane >> 3;                       // 0..7
  const int sslot = ((lane & 7) ^ sub) * 8;        // element offset in row

  const size_t ebase = (size_t)e * S_TOK;
  const ushort_t* Be = B + (size_t)e * NDIM * KDIM;
  const ushort_t* pA[4];
  const ushort_t* pB[4];
#pragma unroll
  for (int j = 0; j < 4; ++j) {
    const int ra = m0 + j * 64 + w * 8 + sub;
    const int tok = (ra < cnt) ? tok_list[ebase + ra] : 0;
    pA[j] = A + (size_t)tok * KDIM + sslot;
    pB[j] = Be + (size_t)(n0 + j * 64 + w * 8 + sub) * KDIM + sslot;
  }

  // ds-read element offsets (swizzled), per fragment and K-half
  int oA[8][2], oB[4][2];
#pragma unroll
  for (int m = 0; m < 8; ++m) {
    const int rr = wr2 + m * 16 + l15;
#pragma unroll
    for (int kk = 0; kk < 2; ++kk)
      oA[m][kk] = rr * BK + (((kk * 4 + l4) ^ (rr & 7)) * 8);
  }
#pragma unroll
  for (int n = 0; n < 4; ++n) {
    const int rr = wc4 + n * 16 + l15;
#pragma unroll
    for (int kk = 0; kk < 2; ++kk)
      oB[n][kk] = rr * BK + (((kk * 4 + l4) ^ (rr & 7)) * 8);
  }

  f32x4 acc[8][4];
#pragma unroll
  for (int i = 0; i < 8; ++i)
#pragma unroll
    for (int j = 0; j < 4; ++j)
      acc[i][j] = (f32x4){0.f, 0.f, 0.f, 0.f};

  // prologue: stage tile 0 into buf 0, drain
#pragma unroll
  for (int j = 0; j < 4; ++j) {
    load_lds16(pA[j], &As[0][j * 4096 + w * 512]);
    load_lds16(pB[j], &Bs[0][j * 4096 + w * 512]);
  }
  __syncthreads();

  for (int t = 0; t < NK; ++t) {
    const int cb = t & 1;
    // issue next-tile stage FIRST: flies under the 24 ds_read + 64 MFMA below
    if (t + 1 < NK) {
      const int kn = (t + 1) * BK;
      const int nb = cb ^ 1;
#pragma unroll
      for (int j = 0; j < 4; ++j) {
        load_lds16(pA[j] + kn, &As[nb][j * 4096 + w * 512]);
        load_lds16(pB[j] + kn, &Bs[nb][j * 4096 + w * 512]);
      }
    }

#pragma unroll
    for (int kk = 0; kk < 2; ++kk) {
      bf16x8 a[8], b[4];
#pragma unroll
      for (int m = 0; m < 8; ++m) a[m] = *(const bf16x8*)&As[cb][oA[m][kk]];
#pragma unroll
      for (int n = 0; n < 4; ++n) b[n] = *(const bf16x8*)&Bs[cb][oB[n][kk]];
#pragma unroll
      for (int m = 0; m < 8; ++m)
#pragma unroll
        for (int n = 0; n < 4; ++n)
          acc[m][n] = __builtin_amdgcn_mfma_f32_16x16x32_bf16(a[m], b[n], acc[m][n], 0, 0, 0);
    }

    __syncthreads();   // ONE barrier/step: next buf staged + cur fully read
  }

  // epilogue
  const float* be = bias + (size_t)e * NDIM;
#pragma unroll
  for (int m = 0; m < 8; ++m) {
#pragma unroll
    for (int rr = 0; rr < 4; ++rr) {
      const int slot = m0 + wr2 + m * 16 + l4 * 4 + rr;
      if (slot >= cnt) continue;
      const int tok = tok_list[ebase + slot];
      if (EPI == 0) {
        ushort_t* hrow = Hout + (size_t)tok * NDIM;
#pragma unroll
        for (int n = 0; n < 4; ++n) {
          const int col = n0 + wc4 + n * 16 + l15;
          hrow[col] = f32_bf16(gelu_f(acc[m][n][rr] + be[col]));
        }
      } else {
        const float p = prob[tok];
        float* orow = out + (size_t)tok * NDIM;
#pragma unroll
        for (int n = 0; n < 4; ++n) {
          const int col = n0 + wc4 + n * 16 + l15;
          orow[col] = (acc[m][n][rr] + be[col]) * p;
        }
      }
    }
  }
}

extern "C" void kernel_launch(void* const* d_in, const int* in_sizes, int n_in,
                              void* d_out, int out_size, void* d_ws, size_t ws_size,
                              hipStream_t stream) {
  const float* x  = (const float*)d_in[0];
  const float* Wg = (const float*)d_in[1];
  const float* W1 = (const float*)d_in[2];
  const float* b1 = (const float*)d_in[3];
  const float* W2 = (const float*)d_in[4];
  const float* b2 = (const float*)d_in[5];
  float* out = (float*)d_out;

  const size_t MB = 1ull << 20;
  char* ws = (char*)d_ws;
  int* counts      = (int*)(ws);                 // 32 B
  int* plan        = (int*)(ws + 4096);          // ~600 B
  float* prob      = (float*)(ws + 64 * 1024);   // 64 KB
  int* tok_list    = (int*)(ws + 128 * 1024);    // 512 KB
  ushort_t* xbf    = (ushort_t*)(ws + 1 * MB);   // 32 MB
  ushort_t* W1bf   = (ushort_t*)(ws + 33 * MB);  // 64 MB
  ushort_t* W2bf   = (ushort_t*)(ws + 97 * MB);  // 64 MB
  ushort_t* H      = (ushort_t*)(ws + 161 * MB); // 128 MB

  zero_counts_kernel<<<1, 64, 0, stream>>>(counts);
  gate_kernel<<<S_TOK / 4, 256, 0, stream>>>(x, Wg, xbf, prob, counts, tok_list);
  plan_kernel<<<1, 64, 0, stream>>>(counts, plan);

  cast2_kernel<<<32768, 256, 0, stream>>>(W1, W1bf, W2, W2bf);

  ffn_kernel<D_DIM, F_DIM, 0><<<(F_DIM / BN) * MT_MAX, 512, 0, stream>>>(
      xbf, W1bf, b1, nullptr, counts, tok_list, plan, H, nullptr);

  ffn_kernel<F_DIM, D_DIM, 1><<<(D_DIM / BN) * MT_MAX, 512, 0, stream>>>(
      H, W2bf, b2, prob, counts, tok_list, plan, nullptr, out);
}

// Round 14
// 731.926 us; speedup vs baseline: 1.1504x; 1.1504x over previous
//
#include <hip/hip_runtime.h>

#define S_TOK 16384   // S*N tokens
#define D_DIM 1024
#define F_DIM 4096
#define E_NUM 8

#define BM 256
#define BN 128
#define BK 32
#define MT_MAX 72     // sum_e ceil(cnt_e/256) <= 64 + 8 = 72

typedef short bf16x8 __attribute__((ext_vector_type(8)));
typedef float f32x4 __attribute__((ext_vector_type(4)));
typedef unsigned short ushort_t;

static __device__ __forceinline__ unsigned short f32_bf16(float f) {
  unsigned u = __float_as_uint(f);
  return (unsigned short)((u + 0x7FFFu + ((u >> 16) & 1u)) >> 16);
}

static __device__ __forceinline__ unsigned int pack_bf16x2(float a, float b) {
  unsigned ua = __float_as_uint(a);
  unsigned ub = __float_as_uint(b);
  unsigned lo = (ua + 0x7FFFu + ((ua >> 16) & 1u)) >> 16;
  unsigned hi = (ub + 0x7FFFu + ((ub >> 16) & 1u)) & 0xFFFF0000u;
  return lo | hi;
}

static __device__ __forceinline__ uint2 cvt_f4_bf4(const float4 v) {
  uint2 r;
  r.x = pack_bf16x2(v.x, v.y);
  r.y = pack_bf16x2(v.z, v.w);
  return r;
}

static __device__ __forceinline__ void load_lds16(const void* g, void* l) {
  __builtin_amdgcn_global_load_lds(g, l, 16, 0, 0);
}

// exact-enough gelu: Abramowitz-Stegun 7.1.26 erf (|err|<=1.5e-7) + fast exp.
static __device__ __forceinline__ float gelu_f(float v) {
  const float u = fabsf(v) * 0.70710678118654752f;
  const float t = 1.0f / (1.0f + 0.3275911f * u);
  const float poly = t * (0.254829592f + t * (-0.284496736f + t * (1.421413741f +
                     t * (-1.453152027f + t * 1.061405429f))));
  const float erfa = 1.0f - poly * __expf(-u * u);
  const float erfv = (v >= 0.0f) ? erfa : -erfa;
  return 0.5f * v * (1.0f + erfv);
}

// ---------------- fp32 -> bf16 cast of W1+W2, also zeroes counts ------------
__global__ void cast2_kernel(const float* __restrict__ w1, ushort_t* __restrict__ o1,
                             const float* __restrict__ w2, ushort_t* __restrict__ o2,
                             int* __restrict__ counts) {
  if (blockIdx.x == 0 && threadIdx.x < E_NUM) counts[threadIdx.x] = 0;
  const int half = 16384;
  const float* src = (blockIdx.x < half) ? w1 : w2;
  ushort_t* dst = (blockIdx.x < half) ? o1 : o2;
  const int b = (blockIdx.x < half) ? blockIdx.x : (blockIdx.x - half);
  const size_t base = ((size_t)b * blockDim.x + threadIdx.x) * 8;
  const float4 v0 = *(const float4*)(src + base);
  const float4 v1 = *(const float4*)(src + base + 4);
  const uint2 a = cvt_f4_bf4(v0), c = cvt_f4_bf4(v1);
  uint4 w; w.x = a.x; w.y = a.y; w.z = c.x; w.w = c.y;
  *(uint4*)(dst + base) = w;
}

// ---------------- gating (+ x cast to bf16) ----------------
__global__ void gate_kernel(const float* __restrict__ x,
                            const float* __restrict__ Wg,
                            ushort_t* __restrict__ xbf,
                            float* __restrict__ prob,
                            int* __restrict__ counts,
                            int* __restrict__ tok_list) {
  const int wv = threadIdx.x >> 6;
  const int lane = threadIdx.x & 63;
  const int t = blockIdx.x * 4 + wv;
  const float* xr = x + (size_t)t * D_DIM;
  ushort_t* xb = xbf + (size_t)t * D_DIM;

  float acc[E_NUM];
#pragma unroll
  for (int e = 0; e < E_NUM; ++e) acc[e] = 0.0f;

#pragma unroll
  for (int i = 0; i < 4; ++i) {
    const int k = i * 256 + lane * 4;
    const float4 v = *(const float4*)(xr + k);
    *(uint2*)(xb + k) = cvt_f4_bf4(v);
#pragma unroll
    for (int e = 0; e < E_NUM; ++e) {
      const float4 w = *(const float4*)(Wg + e * D_DIM + k);
      acc[e] += v.x * w.x + v.y * w.y + v.z * w.z + v.w * w.w;
    }
  }
#pragma unroll
  for (int e = 0; e < E_NUM; ++e) {
#pragma unroll
    for (int off = 32; off > 0; off >>= 1)
      acc[e] += __shfl_xor(acc[e], off, 64);
  }
  if (lane == 0) {
    float m = acc[0]; int bi = 0;
#pragma unroll
    for (int e = 1; e < E_NUM; ++e) {
      if (acc[e] > m) { m = acc[e]; bi = e; }
    }
    float s = 0.0f;
#pragma unroll
    for (int e = 0; e < E_NUM; ++e) s += expf(acc[e] - m);
    prob[t] = 1.0f / s;             // softmax prob of the argmax logit
    int p = atomicAdd(&counts[bi], 1);
    tok_list[bi * S_TOK + p] = t;
  }
}

// BK=32 swizzle (R7-verified, conflicts==0): 64B row = 4 x 16B slots,
// phys = log ^ ((row>>1)&3). Both-sides (rule #21).
#define SWZ32(r) (((r) >> 1) & 3)

// ---------------- grouped GEMM: 256x128, BK=32, dbuf 48KB, 1 barrier/step ----
// R12's tile/wave shape (best measured) + in-step overlap: issue the 3
// global_load_lds for tile t+1 into buf^1 FIRST, then 8 ds_read_b128 + 16
// MFMA per wave on buf, then ONE __syncthreads. LDS 48KB (= R12) -> same
// 2 blocks/CU; plan-free tile mapping (8-iter scan over counts).
template <int KDIM, int NDIM, int EPI>
__launch_bounds__(512, 2)
__global__ void ffn_kernel(const ushort_t* __restrict__ A,
                           const ushort_t* __restrict__ B,
                           const float* __restrict__ bias,
                           const float* __restrict__ prob,
                           const int* __restrict__ counts,
                           const int* __restrict__ tok_list,
                           ushort_t* __restrict__ Hout,
                           float* __restrict__ out) {
  constexpr int NT = NDIM / BN;
  constexpr int NK = KDIM / BK;
  // derive tile table from counts (plan-free)
  int nt_e[E_NUM], ntiles = 0;
#pragma unroll
  for (int i = 0; i < E_NUM; ++i) {
    nt_e[i] = (counts[i] + BM - 1) / BM;
    ntiles += nt_e[i];
  }
  const int live = ntiles * NT;
  if (blockIdx.x >= live) return;
  // runtime-bijective XCD swizzle over the LIVE range (m204 formula)
  const int q = live >> 3, r = live & 7;
  const int xcd = blockIdx.x & 7, idx = blockIdx.x >> 3;
  const int wg = (xcd < r ? xcd * (q + 1) : r * (q + 1) + (xcd - r) * q) + idx;
  const int tile = wg / NT;            // m slow, n fast: A-panel hot per XCD
  const int n0 = (wg % NT) * BN;
  int e = 0, m0 = 0, accb = 0;
#pragma unroll
  for (int i = 0; i < E_NUM; ++i) {
    if (tile >= accb && tile < accb + nt_e[i]) { e = i; m0 = (tile - accb) * BM; }
    accb += nt_e[i];
  }
  const int cnt = counts[e];

  __shared__ ushort_t As[2][BM * BK];   // 2 x 16 KB
  __shared__ ushort_t Bs[2][BN * BK];   // 2 x 8 KB   (48 KB total)

  const int tid = threadIdx.x;
  const int lane = tid & 63;
  const int w = tid >> 6;              // 0..7
  const int wr = (w >> 1) * 64;        // 0,64,128,192 : m-group
  const int wc = (w & 1) * 64;         // 0,64         : n-group
  const int l15 = lane & 15;
  const int l4  = lane >> 4;

  // staging: 4 thr/row (32 el). A: 2 instrs x 128 rows; B: 1 instr x 128 rows.
  const int srow = tid >> 2;                          // 0..127
  const int sslot = ((tid & 3) ^ SWZ32(srow)) * 8;    // pre-swizzled src slot
  const int w256 = w * 256;                           // wave base for 1 instr

  const size_t ebase = (size_t)e * S_TOK;
  const ushort_t* Be = B + (size_t)e * NDIM * KDIM;
  const ushort_t* pA[2];
#pragma unroll
  for (int j = 0; j < 2; ++j) {
    const int ra = m0 + j * 128 + srow;
    const int tok = (ra < cnt) ? tok_list[ebase + ra] : 0;
    pA[j] = A + (size_t)tok * KDIM + sslot;           // SWZ32(r+128)==SWZ32(r)
  }
  const ushort_t* pBr = Be + (size_t)(n0 + srow) * KDIM + sslot;

  // ds-read element offsets (swizzled)
  int oA[4], oB[4];
#pragma unroll
  for (int m = 0; m < 4; ++m) {
    const int rr = wr + m * 16 + l15;
    oA[m] = rr * BK + ((l4 ^ SWZ32(rr)) * 8);
  }
#pragma unroll
  for (int n = 0; n < 4; ++n) {
    const int rr = wc + n * 16 + l15;
    oB[n] = rr * BK + ((l4 ^ SWZ32(rr)) * 8);
  }

  f32x4 acc[4][4];
#pragma unroll
  for (int i = 0; i < 4; ++i)
#pragma unroll
    for (int j = 0; j < 4; ++j)
      acc[i][j] = (f32x4){0.f, 0.f, 0.f, 0.f};

  // prologue: stage tile 0 into buf 0, drain
  load_lds16(pA[0], &As[0][w256 + ((tid & 255) >= 0 ? 0 : 0)]);  // wave-uniform base below
  // NOTE: each instr covers 128 rows = 512 lanes/4. LDS dest must be linear in
  // lane order: instr j base = j*4096 el; lane offset = tid*8 handled by HW.
  // (re-issue correctly:)
  __syncthreads();   // discard the line above if partially wrong? -- no-op safe
  {
    load_lds16(pA[0], &As[0][w * 512]);
    load_lds16(pA[1], &As[0][4096 + w * 512]);
    load_lds16(pBr,   &Bs[0][w * 512]);
  }
  __syncthreads();

  for (int t = 0; t < NK; ++t) {
    const int cb = t & 1;
    // issue next-tile stage FIRST (flies under ds_read+MFMA below)
    if (t + 1 < NK) {
      const int kn = (t + 1) * BK;
      const int nb = cb ^ 1;
      load_lds16(pA[0] + kn, &As[nb][w * 512]);
      load_lds16(pA[1] + kn, &As[nb][4096 + w * 512]);
      load_lds16(pBr + kn,   &Bs[nb][w * 512]);
    }

    bf16x8 a[4], b[4];
#pragma unroll
    for (int i = 0; i < 4; ++i) {
      a[i] = *(const bf16x8*)&As[cb][oA[i]];
      b[i] = *(const bf16x8*)&Bs[cb][oB[i]];
    }
#pragma unroll
    for (int mi = 0; mi < 4; ++mi)
#pragma unroll
      for (int ni = 0; ni < 4; ++ni)
        acc[mi][ni] = __builtin_amdgcn_mfma_f32_16x16x32_bf16(a[mi], b[ni], acc[mi][ni], 0, 0, 0);

    __syncthreads();   // ONE barrier/step: next buf staged + cur fully read
  }

  // epilogue
  const float* be = bias + (size_t)e * NDIM;
#pragma unroll
  for (int mi = 0; mi < 4; ++mi) {
#pragma unroll
    for (int rr = 0; rr < 4; ++rr) {
      const int slot = m0 + wr + mi * 16 + l4 * 4 + rr;
      if (slot >= cnt) continue;
      const int tok = tok_list[ebase + slot];
      if (EPI == 0) {
        ushort_t* hrow = Hout + (size_t)tok * NDIM;
#pragma unroll
        for (int ni = 0; ni < 4; ++ni) {
          const int col = n0 + wc + ni * 16 + l15;
          hrow[col] = f32_bf16(gelu_f(acc[mi][ni][rr] + be[col]));
        }
      } else {
        const float p = prob[tok];
        float* orow = out + (size_t)tok * NDIM;
#pragma unroll
        for (int ni = 0; ni < 4; ++ni) {
          const int col = n0 + wc + ni * 16 + l15;
          orow[col] = (acc[mi][ni][rr] + be[col]) * p;
        }
      }
    }
  }
}

extern "C" void kernel_launch(void* const* d_in, const int* in_sizes, int n_in,
                              void* d_out, int out_size, void* d_ws, size_t ws_size,
                              hipStream_t stream) {
  const float* x  = (const float*)d_in[0];
  const float* Wg = (const float*)d_in[1];
  const float* W1 = (const float*)d_in[2];
  const float* b1 = (const float*)d_in[3];
  const float* W2 = (const float*)d_in[4];
  const float* b2 = (const float*)d_in[5];
  float* out = (float*)d_out;

  const size_t MB = 1ull << 20;
  char* ws = (char*)d_ws;
  int* counts      = (int*)(ws);                 // 32 B
  float* prob      = (float*)(ws + 64 * 1024);   // 64 KB
  int* tok_list    = (int*)(ws + 128 * 1024);    // 512 KB
  ushort_t* xbf    = (ushort_t*)(ws + 1 * MB);   // 32 MB
  ushort_t* W1bf   = (ushort_t*)(ws + 33 * MB);  // 64 MB
  ushort_t* W2bf   = (ushort_t*)(ws + 97 * MB);  // 64 MB
  ushort_t* H      = (ushort_t*)(ws + 161 * MB); // 128 MB

  cast2_kernel<<<32768, 256, 0, stream>>>(W1, W1bf, W2, W2bf, counts);
  gate_kernel<<<S_TOK / 4, 256, 0, stream>>>(x, Wg, xbf, prob, counts, tok_list);

  ffn_kernel<D_DIM, F_DIM, 0><<<(F_DIM / BN) * MT_MAX, 512, 0, stream>>>(
      xbf, W1bf, b1, nullptr, counts, tok_list, H, nullptr);

  ffn_kernel<F_DIM, D_DIM, 1><<<(D_DIM / BN) * MT_MAX, 512, 0, stream>>>(
      H, W2bf, b2, prob, counts, tok_list, nullptr, out);
}